// Round 1
// baseline (181.232 us; speedup 1.0000x reference)
//
#include <hip/hip_runtime.h>
#include <math.h>

// MMD loss, fp16 MFMA. N=M=4096, D=1024, sigma^2=2025.
// Round 11: port of the T3+T4 8-phase/counted-vmcnt schedule (the documented
// prerequisite gate for T2/T5). 256x128 tiles, 8 waves (4Mx2N, per-wave 64x64),
// BK=32, ring-4 LDS (96 KiB), lead-3 staging, s_waitcnt vmcnt(6) at K-tile
// boundaries, raw s_barrier (NO __syncthreads in the loop -> no vmcnt(0) drain,
// which was the old structure's ~70% stall), setprio(1) around each 16-MFMA
// cluster. 3-bit XOR chunk swizzle (phys = chunk ^ ((row>>1)&3)): ds_read_b128
// 2-way max (free); staging fetches inverse-permuted global chunks so the
// linear global_load_lds writes land swizzled (both-sides-or-neither rule).
// Triangular XX/YY coverage with 256x128 tiles: col-tiles j>=2i, w=2 above the
// diagonal square, w=1 for the two straddle tiles; diagonal subtracted
// analytically. 1056 blocks (5 rounds @ 82.5% tail vs 3 rounds @ 69% for 256^2).
// Split-K impossible: exp() needs the full dot product.

typedef _Float16 f16_t;
typedef _Float16 f16x4 __attribute__((ext_vector_type(4)));
typedef _Float16 f16x8 __attribute__((ext_vector_type(8)));
typedef float floatx4 __attribute__((ext_vector_type(4)));

#define NROWS 4096
#define MROWS 4096
#define DDIM  1024
#define BM    256                   // A rows per block
#define BN    128                   // B rows per block
#define BK    32                    // fp16 elements per K-tile (64 B/row)
#define NKT   (DDIM / BK)           // 32 K-tiles
#define NTR   (NROWS / BM)          // 16 row tiles
#define NTC   (NROWS / BN)          // 32 col tiles
#define XXB   272                   // sum_{i=0..15} (32-2i) triangular tiles
#define NBLK  (2 * XXB + NTR * NTC) // 1056 blocks

// ---------------------------------------------------------------- convert
// Wave-per-row: 2048 blocks x 4 waves cover 8192 rows. Each lane loads
// 4 float4 (64 lanes x 16 B = 1 KB per instr, fully coalesced), converts to
// fp16, stores f16x4; norm of the ROUNDED row shuffle-reduced in-wave.
__global__ __launch_bounds__(256) void convert_kernel(
    const float* __restrict__ X, const float* __restrict__ Y,
    f16_t* __restrict__ Xh, f16_t* __restrict__ Yh,
    float* __restrict__ nx, float* __restrict__ ny) {
    const int wid  = threadIdx.x >> 6;
    const int lane = threadIdx.x & 63;
    const int row  = blockIdx.x * 4 + wid;        // 0..8191
    const float* src;
    f16_t* dst;
    float* nrm;
    int r;
    if (row < NROWS) {
        r = row;         src = X + (size_t)r * DDIM;
        dst = Xh + (size_t)r * DDIM;  nrm = nx;
    } else {
        r = row - NROWS; src = Y + (size_t)r * DDIM;
        dst = Yh + (size_t)r * DDIM;  nrm = ny;
    }
    const float4* s4 = (const float4*)src;        // 256 float4 per row
    f16x4* d4 = (f16x4*)dst;
    float s = 0.f;
    #pragma unroll
    for (int c = 0; c < 4; c++) {
        float4 v = s4[c * 64 + lane];
        f16x4 h;
        h[0] = (f16_t)v.x; h[1] = (f16_t)v.y;
        h[2] = (f16_t)v.z; h[3] = (f16_t)v.w;
        d4[c * 64 + lane] = h;
        float h0 = (float)h[0], h1 = (float)h[1];
        float h2 = (float)h[2], h3 = (float)h[3];
        s += h0 * h0 + h1 * h1 + h2 * h2 + h3 * h3;
    }
    #pragma unroll
    for (int off = 32; off > 0; off >>= 1) s += __shfl_down(s, off);
    if (lane == 0) nrm[r] = s;
}

// ---------------------------------------------------------------- main GEMM
// Stage tile tt (clamped: dummy re-stages of tile NKT-1 into dead slots keep
// the vmcnt count uniform through the loop tail; 3 VMEM instrs per call).
#define STAGE(tt_) do {                                                        \
    const int slot_ = (tt_) & 3;                                               \
    const int kk_ = (((tt_) < NKT) ? (tt_) : (NKT - 1)) * BK;                  \
    __builtin_amdgcn_global_load_lds(                                          \
        (const __attribute__((address_space(1))) void*)(gA + kk_),             \
        (__attribute__((address_space(3))) void*)(&ldsA[slot_][wave * 1024]),  \
        16, 0, 0);                                                             \
    __builtin_amdgcn_global_load_lds(                                          \
        (const __attribute__((address_space(1))) void*)(gA + kk_ + 16 * DDIM), \
        (__attribute__((address_space(3))) void*)(&ldsA[slot_][wave * 1024 + 512]), \
        16, 0, 0);                                                             \
    __builtin_amdgcn_global_load_lds(                                          \
        (const __attribute__((address_space(1))) void*)(gB + kk_),             \
        (__attribute__((address_space(3))) void*)(&ldsB[slot_][wave * 512]),   \
        16, 0, 0);                                                             \
  } while (0)

__global__ __launch_bounds__(512, 2) void mmd_mfma(
    const f16_t* __restrict__ Xh, const f16_t* __restrict__ Yh,
    const float* __restrict__ nx, const float* __restrict__ ny,
    double* __restrict__ partials) {
    // Ring-4 double... quadruple buffer: 4 x (A 256x32 + B 128x32) fp16 = 96 KB.
    // Row r of a tile stores logical chunk c (16 B) at phys chunk c ^ ((r>>1)&3).
    __shared__ __align__(16) f16_t ldsA[4][BM * BK];   // 4 x 16 KB
    __shared__ __align__(16) f16_t ldsB[4][BN * BK];   // 4 x  8 KB
    __shared__ double wred[8];

    const int b = blockIdx.x;
    const f16_t *Aptr, *Bptr;
    const float *nAp, *nBp;
    double coef;
    if (b < 2 * XXB) {
        int u = (b < XXB) ? b : b - XXB;
        int i = 0;
        while (u >= NTC - 2 * i) { u -= NTC - 2 * i; i++; }
        const int ti = i, tj = 2 * i + u;         // tj in [2i, 32)
        const double w = (tj >= 2 * i + 2) ? 2.0 : 1.0;  // straddle tiles w=1
        const f16_t* base;
        const float* nb_;
        double denom;
        if (b < XXB) { base = Xh; nb_ = nx; denom = (double)NROWS * (double)(NROWS - 1); }
        else         { base = Yh; nb_ = ny; denom = (double)MROWS * (double)(MROWS - 1); }
        Aptr = base + (size_t)ti * BM * DDIM;
        Bptr = base + (size_t)tj * BN * DDIM;
        nAp = nb_ + ti * BM;  nBp = nb_ + tj * BN;
        coef = w / denom;
    } else {
        const int u = b - 2 * XXB;
        const int ti = u >> 5, tj = u & 31;
        Aptr = Xh + (size_t)ti * BM * DDIM;
        Bptr = Yh + (size_t)tj * BN * DDIM;
        nAp = nx + ti * BM;  nBp = ny + tj * BN;
        coef = -2.0 / ((double)NROWS * (double)MROWS);
    }

    const int tid  = threadIdx.x;
    const int wave = tid >> 6;          // 0..7
    const int lane = tid & 63;
    const int wm   = wave >> 1;         // 0..3 : 4 M-waves x 64 rows
    const int wn   = wave & 1;          // 0..1 : 2 N-waves x 64 cols
    const int m    = lane & 15;
    const int quad = lane >> 4;
    // read-side swizzled chunk offset (f16 units): phys = quad ^ ((row>>1)&3),
    // row = <mult of 16> + m  ->  depends only on m.
    const int sw8  = (quad ^ ((m >> 1) & 3)) * 8;
    const int aoff = (wm * 64 + m) * BK + sw8;      // + s*512 per 16-row frag
    const int boff = (wn * 64 + m) * BK + sw8;

    // staging: per K-tile, wave w covers A rows [w*32, w*32+32) (2 instrs) and
    // B rows [w*16, w*16+16) (1 instr). glds writes linearly: lane l -> row
    // base+(l>>2), phys chunk l&3; fetch the inverse-swizzled global chunk
    // (l&3)^((l>>3)&3) so phys chunk p of row r holds logical p^((r>>1)&3).
    const int lr = lane >> 2;
    const int lc = (lane & 3) ^ ((lane >> 3) & 3);
    const f16_t* gA = Aptr + (size_t)(wave * 32 + lr) * DDIM + lc * 8;
    const f16_t* gB = Bptr + (size_t)(wave * 16 + lr) * DDIM + lc * 8;

    floatx4 acc[4][4];
    #pragma unroll
    for (int i = 0; i < 4; i++)
        #pragma unroll
        for (int j = 0; j < 4; j++) acc[i][j] = (floatx4){0.f, 0.f, 0.f, 0.f};

    // prologue: tiles 0,1,2 in flight; vmcnt(6) -> tile 0 landed (newest 6 =
    // tiles 1,2), publish with barrier.
    STAGE(0); STAGE(1); STAGE(2);
    asm volatile("s_waitcnt vmcnt(6)" ::: "memory");
    __builtin_amdgcn_s_barrier();

    for (int t = 0; t < NKT; ++t) {
        const int slot = t & 3;
        // ds-load register subtiles of tile t (landed: prev boundary vmcnt(6)
        // + barrier). Issued early; consumed after the mid barrier.
        f16x8 ah[4], bh[4];
        #pragma unroll
        for (int s = 0; s < 4; s++) {
            ah[s] = *(const f16x8*)&ldsA[slot][aoff + s * 16 * BK];
            bh[s] = *(const f16x8*)&ldsB[slot][boff + s * 16 * BK];
        }
        // prefetch tile t+3 into slot (t-1)&3 (its readers retired before the
        // previous post-MFMA barrier).
        STAGE(t + 3);
        // K-tile boundary: all but the newest 6 VMEM (tiles t+2,t+3) landed
        // => tile t+1 is in LDS before the next iteration reads it.
        asm volatile("s_waitcnt vmcnt(6)" ::: "memory");
        __builtin_amdgcn_s_barrier();
        __builtin_amdgcn_s_setprio(1);
        #pragma unroll
        for (int i = 0; i < 4; i++)
            #pragma unroll
            for (int j = 0; j < 4; j++)
                acc[i][j] = __builtin_amdgcn_mfma_f32_16x16x32_f16(ah[i], bh[j], acc[i][j], 0, 0, 0);
        __builtin_amdgcn_s_setprio(0);
        // post-MFMA barrier: all waves' ds_reads of this slot retired (lgkmcnt
        // before MFMA) => next phase may overwrite it.
        __builtin_amdgcn_s_barrier();
    }

    // epilogue: C/D layout col=lane&15 (B-row), row=quad*4+reg (A-row).
    // Norm loads here (L3-hot) so no VMEM pollutes the loop's vmcnt counting.
    const float inv_s2 = 1.0f / 2025.0f;
    float nbv[4];
    #pragma unroll
    for (int j = 0; j < 4; j++) nbv[j] = nBp[wn * 64 + j * 16 + m];
    float lsum = 0.f;
    #pragma unroll
    for (int i = 0; i < 4; i++) {
        floatx4 na4 = *(const floatx4*)&nAp[wm * 64 + i * 16 + quad * 4];
        #pragma unroll
        for (int j = 0; j < 4; j++)
            #pragma unroll
            for (int r = 0; r < 4; r++) {
                float arg = (2.f * acc[i][j][r] - na4[r] - nbv[j]) * inv_s2;
                lsum += __expf(arg);
            }
    }

    // in-wave fp64 reduce, 8-wave LDS combine; plain store (no fences).
    double d = (double)lsum;
    #pragma unroll
    for (int off = 32; off > 0; off >>= 1) d += __shfl_down(d, off);
    if (lane == 0) wred[wave] = d;
    __syncthreads();
    if (tid == 0) {
        double s = 0.0;
        #pragma unroll
        for (int w = 0; w < 8; w++) s += wred[w];
        partials[b] = s * coef;
    }
}

__global__ __launch_bounds__(256) void final_reduce(const double* __restrict__ partials,
                                                    float* __restrict__ out) {
    __shared__ double red[256];
    int t = threadIdx.x;
    double s = 0.0;
    for (int i = t; i < NBLK; i += 256) s += partials[i];
    red[t] = s;
    __syncthreads();
    for (int off = 128; off > 0; off >>= 1) {
        if (t < off) red[t] += red[t + off];
        __syncthreads();
    }
    if (t == 0) {
        // analytic diagonal subtraction: 1/(n-1) + 1/(m-1)
        double mmd = red[0] - 1.0 / (double)(NROWS - 1) - 1.0 / (double)(MROWS - 1);
        out[0] = (float)mmd;
    }
}

extern "C" void kernel_launch(void* const* d_in, const int* in_sizes, int n_in,
                              void* d_out, int out_size, void* d_ws, size_t ws_size,
                              hipStream_t stream) {
    const float* X = (const float*)d_in[0];   // inputs  [4096,1024] fp32
    const float* Y = (const float*)d_in[1];   // samples [4096,1024] fp32
    float* out = (float*)d_out;

    // workspace: partials | nx | ny | Xh | Yh  (~16.7 MB)
    char* p = (char*)d_ws;
    double* partials = (double*)p;            p += ((size_t)NBLK * sizeof(double) + 255) & ~255ULL;
    float* nx = (float*)p;                    p += (size_t)NROWS * sizeof(float);
    float* ny = (float*)p;                    p += (size_t)MROWS * sizeof(float);
    f16_t* Xh = (f16_t*)p;                    p += (size_t)NROWS * DDIM * sizeof(f16_t);
    f16_t* Yh = (f16_t*)p;

    convert_kernel<<<(NROWS + MROWS) / 4, 256, 0, stream>>>(X, Y, Xh, Yh, nx, ny);
    mmd_mfma<<<NBLK, 512, 0, stream>>>(Xh, Yh, nx, ny, partials);
    final_reduce<<<1, 256, 0, stream>>>(partials, out);
}

// Round 2
// 165.546 us; speedup vs baseline: 1.0948x; 1.0948x over previous
//
#include <hip/hip_runtime.h>
#include <math.h>

// MMD loss, fp16 MFMA. N=M=4096, D=1024, sigma^2=2025.
// Round 12: K-MAJOR PANEL PACKING. Round-11 post-mortem: bank conflicts -> 0
// but 1400cy/phase of vmcnt stall; staging = 64B-granular requests at 2KB
// stride pinned the memory path at ~1-1.35 TB/s (both R10 and R11!). Fix:
// convert_kernel writes Xp/Yp in [kt][row][32] panel layout, so each K-tile
// stage of a 256-row panel is ONE contiguous 16KB block; every glds instr
// reads 1KB contiguous. Core loop (ring-4 LDS, counted vmcnt(6), raw
// s_barrier, 3-bit... 2-bit XOR granule swizzle, setprio) byte-identical to
// round 11 -- the only delta is global staging/store addressing.
// Grid: 256x128 tiles, triangular XX/YY (j>=2i, w=2 above diag square, w=1
// straddle), diagonal analytic. 1056 blocks.

typedef _Float16 f16_t;
typedef _Float16 f16x4 __attribute__((ext_vector_type(4)));
typedef _Float16 f16x8 __attribute__((ext_vector_type(8)));
typedef float floatx4 __attribute__((ext_vector_type(4)));

#define NROWS 4096
#define MROWS 4096
#define DDIM  1024
#define BM    256                   // A rows per block
#define BN    128                   // B rows per block
#define BK    32                    // fp16 elements per K-tile (64 B/row)
#define NKT   (DDIM / BK)           // 32 K-tiles
#define PSTRIDE (4096 * BK)         // f16 elems per packed K-panel (131072)
#define NTR   (NROWS / BM)          // 16 row tiles
#define NTC   (NROWS / BN)          // 32 col tiles
#define XXB   272                   // sum_{i=0..15} (32-2i) triangular tiles
#define NBLK  (2 * XXB + NTR * NTC) // 1056 blocks

// ---------------------------------------------------------------- convert
// Wave-per-row; fully coalesced float4 loads. Stores go to the PACKED layout
// Xp[kt][row][32]: lane l, iter c covers k = c*256 + l*4 -> panel c*8+(l>>3),
// pos (l&7)*4. Per (c, panel-group): 8 lanes x 8B = 64B contiguous. Norm of
// the ROUNDED row shuffle-reduced in-wave.
__global__ __launch_bounds__(256) void convert_kernel(
    const float* __restrict__ X, const float* __restrict__ Y,
    f16_t* __restrict__ Xp, f16_t* __restrict__ Yp,
    float* __restrict__ nx, float* __restrict__ ny) {
    const int wid  = threadIdx.x >> 6;
    const int lane = threadIdx.x & 63;
    const int row  = blockIdx.x * 4 + wid;        // 0..8191
    const float* src;
    f16_t* dstp;
    float* nrm;
    int r;
    if (row < NROWS) {
        r = row;         src = X + (size_t)r * DDIM;
        dstp = Xp;  nrm = nx;
    } else {
        r = row - NROWS; src = Y + (size_t)r * DDIM;
        dstp = Yp;  nrm = ny;
    }
    const float4* s4 = (const float4*)src;        // 256 float4 per row
    float s = 0.f;
    #pragma unroll
    for (int c = 0; c < 4; c++) {
        float4 v = s4[c * 64 + lane];
        f16x4 h;
        h[0] = (f16_t)v.x; h[1] = (f16_t)v.y;
        h[2] = (f16_t)v.z; h[3] = (f16_t)v.w;
        // k = c*256 + lane*4 -> kt = c*8 + (lane>>3), pos = (lane&7)*4
        *(f16x4*)(dstp + (size_t)(c * 8 + (lane >> 3)) * PSTRIDE
                       + (size_t)r * BK + (lane & 7) * 4) = h;
        float h0 = (float)h[0], h1 = (float)h[1];
        float h2 = (float)h[2], h3 = (float)h[3];
        s += h0 * h0 + h1 * h1 + h2 * h2 + h3 * h3;
    }
    #pragma unroll
    for (int off = 32; off > 0; off >>= 1) s += __shfl_down(s, off);
    if (lane == 0) nrm[r] = s;
}

// ---------------------------------------------------------------- main GEMM
// Stage tile tt (clamped: dummy re-stages of tile NKT-1 into dead slots keep
// the vmcnt count uniform through the loop tail; 3 VMEM instrs per call).
// Packed layout: per-tile addend is tt*PSTRIDE; each instr reads 1KB
// CONTIGUOUS (16 rows x 64B, rows now 32-f16 apart in the panel).
#define STAGE(tt_) do {                                                        \
    const int slot_ = (tt_) & 3;                                               \
    const size_t kk_ = (size_t)(((tt_) < NKT) ? (tt_) : (NKT - 1)) * PSTRIDE;  \
    __builtin_amdgcn_global_load_lds(                                          \
        (const __attribute__((address_space(1))) void*)(gA + kk_),             \
        (__attribute__((address_space(3))) void*)(&ldsA[slot_][wave * 1024]),  \
        16, 0, 0);                                                             \
    __builtin_amdgcn_global_load_lds(                                          \
        (const __attribute__((address_space(1))) void*)(gA + kk_ + 16 * BK),   \
        (__attribute__((address_space(3))) void*)(&ldsA[slot_][wave * 1024 + 512]), \
        16, 0, 0);                                                             \
    __builtin_amdgcn_global_load_lds(                                          \
        (const __attribute__((address_space(1))) void*)(gB + kk_),             \
        (__attribute__((address_space(3))) void*)(&ldsB[slot_][wave * 512]),   \
        16, 0, 0);                                                             \
  } while (0)

__global__ __launch_bounds__(512, 2) void mmd_mfma(
    const f16_t* __restrict__ Xp, const f16_t* __restrict__ Yp,
    const float* __restrict__ nx, const float* __restrict__ ny,
    double* __restrict__ partials) {
    // Ring-4 buffer: 4 x (A 256x32 + B 128x32) fp16 = 96 KB.
    // Row r of a tile stores logical chunk c (16 B) at phys chunk c ^ f(r),
    // f(r) = ((r&15)>>1)&3 (verified 0-conflict in round 11).
    __shared__ __align__(16) f16_t ldsA[4][BM * BK];   // 4 x 16 KB
    __shared__ __align__(16) f16_t ldsB[4][BN * BK];   // 4 x  8 KB
    __shared__ double wred[8];

    const int b = blockIdx.x;
    const f16_t *Abase, *Bbase;
    const float *nAp, *nBp;
    int arow0, brow0;                 // panel row offsets of the tiles
    double coef;
    if (b < 2 * XXB) {
        int u = (b < XXB) ? b : b - XXB;
        int i = 0;
        while (u >= NTC - 2 * i) { u -= NTC - 2 * i; i++; }
        const int ti = i, tj = 2 * i + u;         // tj in [2i, 32)
        const double w = (tj >= 2 * i + 2) ? 2.0 : 1.0;  // straddle tiles w=1
        const f16_t* base;
        const float* nb_;
        double denom;
        if (b < XXB) { base = Xp; nb_ = nx; denom = (double)NROWS * (double)(NROWS - 1); }
        else         { base = Yp; nb_ = ny; denom = (double)MROWS * (double)(MROWS - 1); }
        Abase = base; Bbase = base;
        arow0 = ti * BM;  brow0 = tj * BN;
        nAp = nb_ + ti * BM;  nBp = nb_ + tj * BN;
        coef = w / denom;
    } else {
        const int u = b - 2 * XXB;
        const int ti = u >> 5, tj = u & 31;
        Abase = Xp; Bbase = Yp;
        arow0 = ti * BM;  brow0 = tj * BN;
        nAp = nx + ti * BM;  nBp = ny + tj * BN;
        coef = -2.0 / ((double)NROWS * (double)MROWS);
    }

    const int tid  = threadIdx.x;
    const int wave = tid >> 6;          // 0..7
    const int lane = tid & 63;
    const int wm   = wave >> 1;         // 0..3 : 4 M-waves x 64 rows
    const int wn   = wave & 1;          // 0..1 : 2 N-waves x 64 cols
    const int m    = lane & 15;
    const int quad = lane >> 4;
    // read-side swizzled chunk offset (f16 units): phys = quad ^ ((row>>1)&3)
    const int sw8  = (quad ^ ((m >> 1) & 3)) * 8;
    const int aoff = (wm * 64 + m) * BK + sw8;      // + s*512 per 16-row frag
    const int boff = (wn * 64 + m) * BK + sw8;

    // staging: per K-tile, wave w covers A rows [w*32, w*32+32) (2 instrs) and
    // B rows [w*16, w*16+16) (1 instr). glds writes linearly: lane l -> row
    // base+(l>>2), phys chunk l&3; fetch the inverse-swizzled global chunk
    // (l&3)^((l>>3)&3) so phys chunk p of row r holds logical p^((r>>1)&3).
    // PACKED: panel row stride is BK (=32 f16, 64B); per-instr block is 1KB
    // contiguous.
    const int lr = lane >> 2;
    const int lc = (lane & 3) ^ ((lane >> 3) & 3);
    const f16_t* gA = Abase + (size_t)(arow0 + wave * 32 + lr) * BK + lc * 8;
    const f16_t* gB = Bbase + (size_t)(brow0 + wave * 16 + lr) * BK + lc * 8;

    floatx4 acc[4][4];
    #pragma unroll
    for (int i = 0; i < 4; i++)
        #pragma unroll
        for (int j = 0; j < 4; j++) acc[i][j] = (floatx4){0.f, 0.f, 0.f, 0.f};

    // prologue: tiles 0,1,2 in flight; vmcnt(6) -> tile 0 landed (newest 6 =
    // tiles 1,2), publish with barrier.
    STAGE(0); STAGE(1); STAGE(2);
    asm volatile("s_waitcnt vmcnt(6)" ::: "memory");
    __builtin_amdgcn_s_barrier();

    for (int t = 0; t < NKT; ++t) {
        const int slot = t & 3;
        // ds-load register subtiles of tile t (landed: prev boundary vmcnt(6)
        // + barrier). Issued early; consumed after the mid barrier.
        f16x8 ah[4], bh[4];
        #pragma unroll
        for (int s = 0; s < 4; s++) {
            ah[s] = *(const f16x8*)&ldsA[slot][aoff + s * 16 * BK];
            bh[s] = *(const f16x8*)&ldsB[slot][boff + s * 16 * BK];
        }
        // prefetch tile t+3 into slot (t-1)&3 (its readers retired before the
        // previous post-MFMA barrier).
        STAGE(t + 3);
        // K-tile boundary: all but the newest 6 VMEM (tiles t+2,t+3) landed
        // => tile t+1 is in LDS before the next iteration reads it.
        asm volatile("s_waitcnt vmcnt(6)" ::: "memory");
        __builtin_amdgcn_s_barrier();
        __builtin_amdgcn_s_setprio(1);
        #pragma unroll
        for (int i = 0; i < 4; i++)
            #pragma unroll
            for (int j = 0; j < 4; j++)
                acc[i][j] = __builtin_amdgcn_mfma_f32_16x16x32_f16(ah[i], bh[j], acc[i][j], 0, 0, 0);
        __builtin_amdgcn_s_setprio(0);
        // post-MFMA barrier: all waves' ds_reads of this slot retired (lgkmcnt
        // before MFMA) => next phase may overwrite it.
        __builtin_amdgcn_s_barrier();
    }

    // epilogue: C/D layout col=lane&15 (B-row), row=quad*4+reg (A-row).
    // Norm loads here (L3-hot) so no VMEM pollutes the loop's vmcnt counting.
    const float inv_s2 = 1.0f / 2025.0f;
    float nbv[4];
    #pragma unroll
    for (int j = 0; j < 4; j++) nbv[j] = nBp[wn * 64 + j * 16 + m];
    float lsum = 0.f;
    #pragma unroll
    for (int i = 0; i < 4; i++) {
        floatx4 na4 = *(const floatx4*)&nAp[wm * 64 + i * 16 + quad * 4];
        #pragma unroll
        for (int j = 0; j < 4; j++)
            #pragma unroll
            for (int r = 0; r < 4; r++) {
                float arg = (2.f * acc[i][j][r] - na4[r] - nbv[j]) * inv_s2;
                lsum += __expf(arg);
            }
    }

    // in-wave fp64 reduce, 8-wave LDS combine; plain store (no fences).
    double d = (double)lsum;
    #pragma unroll
    for (int off = 32; off > 0; off >>= 1) d += __shfl_down(d, off);
    if (lane == 0) wred[wave] = d;
    __syncthreads();
    if (tid == 0) {
        double s = 0.0;
        #pragma unroll
        for (int w = 0; w < 8; w++) s += wred[w];
        partials[b] = s * coef;
    }
}

__global__ __launch_bounds__(256) void final_reduce(const double* __restrict__ partials,
                                                    float* __restrict__ out) {
    __shared__ double red[256];
    int t = threadIdx.x;
    double s = 0.0;
    for (int i = t; i < NBLK; i += 256) s += partials[i];
    red[t] = s;
    __syncthreads();
    for (int off = 128; off > 0; off >>= 1) {
        if (t < off) red[t] += red[t + off];
        __syncthreads();
    }
    if (t == 0) {
        // analytic diagonal subtraction: 1/(n-1) + 1/(m-1)
        double mmd = red[0] - 1.0 / (double)(NROWS - 1) - 1.0 / (double)(MROWS - 1);
        out[0] = (float)mmd;
    }
}

extern "C" void kernel_launch(void* const* d_in, const int* in_sizes, int n_in,
                              void* d_out, int out_size, void* d_ws, size_t ws_size,
                              hipStream_t stream) {
    const float* X = (const float*)d_in[0];   // inputs  [4096,1024] fp32
    const float* Y = (const float*)d_in[1];   // samples [4096,1024] fp32
    float* out = (float*)d_out;

    // workspace: partials | nx | ny | Xp | Yp  (~16.7 MB)
    char* p = (char*)d_ws;
    double* partials = (double*)p;            p += ((size_t)NBLK * sizeof(double) + 255) & ~255ULL;
    float* nx = (float*)p;                    p += (size_t)NROWS * sizeof(float);
    float* ny = (float*)p;                    p += (size_t)MROWS * sizeof(float);
    f16_t* Xp = (f16_t*)p;                    p += (size_t)NROWS * DDIM * sizeof(f16_t);
    f16_t* Yp = (f16_t*)p;

    convert_kernel<<<(NROWS + MROWS) / 4, 256, 0, stream>>>(X, Y, Xp, Yp, nx, ny);
    mmd_mfma<<<NBLK, 512, 0, stream>>>(Xp, Yp, nx, ny, partials);
    final_reduce<<<1, 256, 0, stream>>>(partials, out);
}